// Round 12
// baseline (114.609 us; speedup 1.0000x reference)
//
#include <hip/hip_runtime.h>
#include <hip/hip_bf16.h>

// QueryGrouper: ball_query (first-K-in-index-order within radius) + grouping.
// B=4, N=8192, M=2048, C=128, K=32, radius=0.1, use_xyz from out_size.
//
// R12 (= R11 resubmitted after container failure): VISIBILITY DIAGNOSTIC.
// R10 (62.6us) is ambiguous between {ball 15, B1 39} and {ball 30, B1 25}.
// This round: gather phase B x4 with PLAIN float4 stores (R8's measured
// 16.2us/pass mode) -> gather ~92-106us, guaranteed into rocprof top-5
// (R9 missed at 81.6 vs 81.3 cutoff). Readouts: gather dur (-> ball by
// subtraction), FETCH_SIZE (RFO?), VALUBusy/occupancy/LDS conflicts, total.

#define K_NEIGH 32
// f32(0.010000000000000002) — matches JAX weak-typed radius*radius bit-exactly.
#define R2_F32 0.009999999776482582f
#define CCH 128
#define NPTS 8192
#define MQ 2048

__global__ __launch_bounds__(256) void ball_query_xyz_kernel(
    const float* __restrict__ xyz,      // (B,3,N)
    const float* __restrict__ new_xyz,  // (B,3,M)
    int* __restrict__ idxb,             // (B*M, K)
    float* __restrict__ out0,           // (B, CO, M, K)
    float* __restrict__ out1,           // (B, 3, M, K)
    int N, int M, int C, int use_xyz)
{
    __shared__ int lidx[4][K_NEIGH];
    const int wave = threadIdx.x >> 6;
    const int lane = threadIdx.x & 63;
    const int q = blockIdx.x * 4 + wave;           // query id in [0, B*M)
    const int b = q / M;
    const int m = q - b * M;

    const float* xb = xyz + (size_t)b * 3 * N;
    const float* x0 = xb;
    const float* x1 = xb + N;
    const float* x2 = xb + 2 * N;
    const float* nb = new_xyz + (size_t)b * 3 * M;
    const float qx = nb[m];
    const float qy = nb[M + m];
    const float qz = nb[2 * M + m];

    int cnt = 0;
    int ff  = 0;   // pad value: first in-ball index, or 0 if none
    const unsigned long long below = (1ull << lane) - 1ull;

    // full scan, unrolled x4 (no early exit)
    for (int t0 = 0; t0 < N; t0 += 256) {
        const int i = t0 + lane;
        const float ax0 = x0[i];       const float ay0 = x1[i];       const float az0 = x2[i];
        const float ax1 = x0[i + 64];  const float ay1 = x1[i + 64];  const float az1 = x2[i + 64];
        const float ax2 = x0[i + 128]; const float ay2 = x1[i + 128]; const float az2 = x2[i + 128];
        const float ax3 = x0[i + 192]; const float ay3 = x1[i + 192]; const float az3 = x2[i + 192];

        // match JAX: sub, square (no FMA), left-to-right sum, all f32 RN
        #define D2(ax, ay, az) \
            __fadd_rn(__fadd_rn(__fmul_rn((ax) - qx, (ax) - qx), \
                                __fmul_rn((ay) - qy, (ay) - qy)), \
                      __fmul_rn((az) - qz, (az) - qz))
        const bool in0 = D2(ax0, ay0, az0) < R2_F32;
        const bool in1 = D2(ax1, ay1, az1) < R2_F32;
        const bool in2 = D2(ax2, ay2, az2) < R2_F32;
        const bool in3 = D2(ax3, ay3, az3) < R2_F32;
        #undef D2

        const unsigned long long m0 = __ballot(in0);
        const unsigned long long m1 = __ballot(in1);
        const unsigned long long m2 = __ballot(in2);
        const unsigned long long m3 = __ballot(in3);

        #define SUBIT(mm, inn, ii)                                            \
            if (mm) {                                                         \
                if (cnt == 0) ff = (ii) - lane + (__ffsll(mm) - 1);           \
                if (inn) {                                                    \
                    const int pos = cnt + __popcll((mm) & below);             \
                    if (pos < K_NEIGH) lidx[wave][pos] = (ii);                \
                }                                                             \
                cnt += __popcll(mm);                                          \
            }
        SUBIT(m0, in0, i)
        SUBIT(m1, in1, i + 64)
        SUBIT(m2, in2, i + 128)
        SUBIT(m3, in3, i + 192)
        #undef SUBIT
    }

    // make this wave's LDS writes visible to its own lanes
    asm volatile("s_waitcnt lgkmcnt(0)" ::: "memory");

    if (lane < K_NEIGH) {
        const int j = (lane < cnt) ? lidx[wave][lane] : ff;
        idxb[(size_t)q * K_NEIGH + lane] = j;
        const float gx = x0[j] - qx;
        const float gy = x1[j] - qy;
        const float gz = x2[j] - qz;
        const size_t MK = (size_t)M * K_NEIGH;
        const size_t o1 = (size_t)b * 3 * MK + (size_t)m * K_NEIGH + lane;
        out1[o1]          = gx;
        out1[o1 + MK]     = gy;
        out1[o1 + 2 * MK] = gz;
        if (use_xyz) {
            const size_t o0 = (size_t)b * (C + 3) * MK + (size_t)m * K_NEIGH + lane;
            out0[o0]          = gx;
            out0[o0 + MK]     = gy;
            out0[o0 + 2 * MK] = gz;
        }
    }
}

// Fixed geometry: B=4, N=8192, M=2048, C=128. Grid = 256 blocks x 1024 thr.
// DIAGNOSTIC: phase B x4 with PLAIN float4 stores (R8's measured mode).
__global__ __launch_bounds__(1024, 4) void gather_diag4_kernel(
    const float* __restrict__ feat,  // (B,C,N)
    const int* __restrict__ idxb,    // (B*M,K)
    float* __restrict__ out0,        // (B,CO,M,K)
    int use_xyz)
{
    __shared__ float sf[2 * NPTS];   // 64 KB: [0,N) = ch c0, [N,2N) = ch c0+1

    const int t   = threadIdx.x;
    const int bid = blockIdx.x;
    const int b   = (bid & 7) >> 1;                 // 0..3
    const int cg  = ((bid >> 3) << 1) | (bid & 1);  // 0..63
    const int c0  = cg * 2;

    // ---- Phase A: idx prefetch (regs) + feat stage (LDS) ----
    const int4* ip4 = (const int4*)(idxb + (size_t)b * MQ * K_NEIGH);
    int4 jj[16];
    #pragma unroll
    for (int i = 0; i < 16; ++i) jj[i] = ip4[i * 1024 + t];

    const float4* fv = (const float4*)(feat + ((size_t)b * CCH + c0) * NPTS);
    #pragma unroll
    for (int r = 0; r < 4; ++r)
        ((float4*)sf)[t + r * 1024] = fv[t + r * 1024];
    __syncthreads();

    // ---- Phase B x4 (diagnostic): pure LDS-read + plain float4 stores ----
    const size_t MK = (size_t)MQ * K_NEIGH;
    const int CO   = use_xyz ? (CCH + 3) : CCH;
    const int coff = use_xyz ? 3 : 0;
    float* o0 = out0 + ((size_t)b * CO + coff + c0) * MK;
    float* o1 = o0 + MK;

    for (int pass = 0; pass < 4; ++pass) {
        #pragma unroll
        for (int i = 0; i < 16; ++i) {
            const int p = i * 4096 + 4 * t;      // flat (m,k) base, k-aligned x4
            const int4 j4 = jj[i];
            float4 s0, s1;
            s0.x = sf[j4.x]; s0.y = sf[j4.y]; s0.z = sf[j4.z]; s0.w = sf[j4.w];
            s1.x = sf[NPTS + j4.x]; s1.y = sf[NPTS + j4.y];
            s1.z = sf[NPTS + j4.z]; s1.w = sf[NPTS + j4.w];
            *(float4*)(o0 + p) = s0;
            *(float4*)(o1 + p) = s1;
        }
        __syncthreads();   // fence between passes (prevents dead-store elim)
    }
}

// Fallback gather (any shape): R1 structure.
__global__ __launch_bounds__(256) void gather_kernel(
    const float* __restrict__ xyz, const float* __restrict__ new_xyz,
    const float* __restrict__ feat, const int* __restrict__ idxb,
    float* __restrict__ out0, float* __restrict__ out1,
    int N, int M, int C, int use_xyz)
{
    const int tid = threadIdx.x;
    const int k = tid & 31;
    const int mloc = tid >> 5;
    const int mchunks = M >> 3;
    const int b = blockIdx.x / mchunks;
    const int m = (blockIdx.x - b * mchunks) * 8 + mloc;
    const int q = b * M + m;
    const int j = idxb[(size_t)q * K_NEIGH + k];
    const size_t xb = (size_t)b * 3 * N;
    const size_t nb = (size_t)b * 3 * M;
    const float gx = xyz[xb + j]         - new_xyz[nb + m];
    const float gy = xyz[xb + N + j]     - new_xyz[nb + M + m];
    const float gz = xyz[xb + 2 * N + j] - new_xyz[nb + 2 * M + m];
    const size_t MK = (size_t)M * K_NEIGH;
    const size_t o1 = (size_t)b * 3 * MK + (size_t)m * K_NEIGH + k;
    out1[o1] = gx; out1[o1 + MK] = gy; out1[o1 + 2 * MK] = gz;
    const int CO = use_xyz ? (C + 3) : C;
    size_t o0 = (size_t)b * CO * MK + (size_t)m * K_NEIGH + k;
    if (use_xyz) {
        out0[o0] = gx; out0[o0 + MK] = gy; out0[o0 + 2 * MK] = gz;
        o0 += 3 * MK;
    }
    const float* fb = feat + (size_t)b * C * N;
    #pragma unroll 4
    for (int c = 0; c < C; c += 4) {
        const float v0 = fb[(size_t)c * N + j];
        const float v1 = fb[(size_t)(c + 1) * N + j];
        const float v2 = fb[(size_t)(c + 2) * N + j];
        const float v3 = fb[(size_t)(c + 3) * N + j];
        out0[o0 + (size_t)c * MK]       = v0;
        out0[o0 + (size_t)(c + 1) * MK] = v1;
        out0[o0 + (size_t)(c + 2) * MK] = v2;
        out0[o0 + (size_t)(c + 3) * MK] = v3;
    }
}

extern "C" void kernel_launch(void* const* d_in, const int* in_sizes, int n_in,
                              void* d_out, int out_size, void* d_ws, size_t ws_size,
                              hipStream_t stream) {
    const float* new_xyz = (const float*)d_in[0];   // (B,3,M)
    const float* xyz     = (const float*)d_in[1];   // (B,3,N)
    const float* feat    = (const float*)d_in[2];   // (B,C,N)

    const int B = 4;                       // fixed by harness setup
    const int M = in_sizes[0] / (3 * B);   // 2048
    const int N = in_sizes[1] / (3 * B);   // 8192
    const int C = in_sizes[2] / (B * N);   // 128

    const long long sz_with = (long long)B * (C + 6) * M * K_NEIGH;
    const int use_xyz = (out_size == sz_with) ? 1 : 0;

    float* out0 = (float*)d_out;
    float* out1 = out0 + (size_t)B * (use_xyz ? (C + 3) : C) * M * K_NEIGH;

    int* idxb = (int*)d_ws;  // B*M*K ints = 1 MB
    const size_t idx_bytes = (size_t)B * M * K_NEIGH * sizeof(int);

    const bool fast = (B == 4) && (N == NPTS) && (M == MQ) && (C == CCH)
                      && (ws_size >= idx_bytes) && (N % 256 == 0);

    ball_query_xyz_kernel<<<(B * M) / 4, 256, 0, stream>>>(
        xyz, new_xyz, idxb, out0, out1, N, M, C, use_xyz);

    if (fast) {
        gather_diag4_kernel<<<256, 1024, 0, stream>>>(feat, idxb, out0, use_xyz);
    } else {
        gather_kernel<<<B * (M / 8), 256, 0, stream>>>(xyz, new_xyz, feat, idxb,
                                                       out0, out1, N, M, C, use_xyz);
    }
}

// Round 13
// 53.211 us; speedup vs baseline: 2.1539x; 2.1539x over previous
//
#include <hip/hip_runtime.h>
#include <hip/hip_bf16.h>

// QueryGrouper: ball_query (first-K-in-index-order within radius) + grouping.
// B=4, N=8192, M=2048, C=128, K=32, radius=0.1, use_xyz from out_size.
//
// R13: R12's counters closed the books: gather one-pass ~22us is at the HBM
// write roofline (FETCH 9.3MB -> no RFO; 6.26 TB/s). Residual is ball ~26us,
// L2-BW-bound (8192 query-waves x 96KB xyz = 786MB of L2 reads). Fix: 8
// queries per 512-thr block share LDS-staged xyz chunks (2048 pts, 24KB) ->
// L2 traffic /8. Gather: one-pass, plain float4 stores (R12-validated mode).

#define K_NEIGH 32
// f32(0.010000000000000002) — matches JAX weak-typed radius*radius bit-exactly.
#define R2_F32 0.009999999776482582f
#define CCH 128
#define NPTS 8192
#define MQ 2048

// ---- fast-path ball: 512 thr = 8 waves = 8 queries, LDS-chunked xyz ----
__global__ __launch_bounds__(512) void ball_lds_kernel(
    const float* __restrict__ xyz,      // (B,3,N)
    const float* __restrict__ new_xyz,  // (B,3,M)
    int* __restrict__ idxb,             // (B*M, K)
    float* __restrict__ out0,           // (B, CO, M, K)
    float* __restrict__ out1,           // (B, 3, M, K)
    int use_xyz)
{
    constexpr int CH = 2048;
    __shared__ float sx[CH], sy[CH], sz[CH];   // 24 KB
    __shared__ int lidx[8][K_NEIGH];

    const int tid  = threadIdx.x;
    const int wave = tid >> 6;
    const int lane = tid & 63;
    const int q = blockIdx.x * 8 + wave;       // 8 queries/block, same batch
    const int b = q / MQ;
    const int m = q - b * MQ;

    const float* x0 = xyz + (size_t)b * 3 * NPTS;
    const float* x1 = x0 + NPTS;
    const float* x2 = x1 + NPTS;
    const float* nb = new_xyz + (size_t)b * 3 * MQ;
    const float qx = nb[m];
    const float qy = nb[MQ + m];
    const float qz = nb[2 * MQ + m];

    int cnt = 0;
    int ff  = 0;   // pad value: first in-ball index, or 0 if none
    const unsigned long long below = (1ull << lane) - 1ull;

    for (int c0 = 0; c0 < NPTS; c0 += CH) {
        // stage chunk: 512 thr x float4 per array (2048 floats each)
        const int i4 = tid * 4;
        *(float4*)&sx[i4] = *(const float4*)&x0[c0 + i4];
        *(float4*)&sy[i4] = *(const float4*)&x1[c0 + i4];
        *(float4*)&sz[i4] = *(const float4*)&x2[c0 + i4];
        __syncthreads();

        for (int g = 0; g < CH; g += 256) {
            const int i = g + lane;
            const float ax0 = sx[i];       const float ay0 = sy[i];       const float az0 = sz[i];
            const float ax1 = sx[i + 64];  const float ay1 = sy[i + 64];  const float az1 = sz[i + 64];
            const float ax2 = sx[i + 128]; const float ay2 = sy[i + 128]; const float az2 = sz[i + 128];
            const float ax3 = sx[i + 192]; const float ay3 = sy[i + 192]; const float az3 = sz[i + 192];

            // match JAX: sub, square (no FMA), left-to-right sum, all f32 RN
            #define D2(ax, ay, az) \
                __fadd_rn(__fadd_rn(__fmul_rn((ax) - qx, (ax) - qx), \
                                    __fmul_rn((ay) - qy, (ay) - qy)), \
                          __fmul_rn((az) - qz, (az) - qz))
            const bool in0 = D2(ax0, ay0, az0) < R2_F32;
            const bool in1 = D2(ax1, ay1, az1) < R2_F32;
            const bool in2 = D2(ax2, ay2, az2) < R2_F32;
            const bool in3 = D2(ax3, ay3, az3) < R2_F32;
            #undef D2

            const unsigned long long m0 = __ballot(in0);
            const unsigned long long m1 = __ballot(in1);
            const unsigned long long m2 = __ballot(in2);
            const unsigned long long m3 = __ballot(in3);

            const int gi = c0 + g + lane;   // global index of slot-0 point
            #define SUBIT(mm, inn, ii)                                        \
                if (mm) {                                                     \
                    if (cnt == 0) ff = (ii) - lane + (__ffsll(mm) - 1);       \
                    if (inn) {                                                \
                        const int pos = cnt + __popcll((mm) & below);         \
                        if (pos < K_NEIGH) lidx[wave][pos] = (ii);            \
                    }                                                         \
                    cnt += __popcll(mm);                                      \
                }
            SUBIT(m0, in0, gi)
            SUBIT(m1, in1, gi + 64)
            SUBIT(m2, in2, gi + 128)
            SUBIT(m3, in3, gi + 192)
            #undef SUBIT
        }
        __syncthreads();
    }

    // lidx writes already drained by the final barrier; belt-and-braces:
    asm volatile("s_waitcnt lgkmcnt(0)" ::: "memory");

    if (lane < K_NEIGH) {
        const int j = (lane < cnt) ? lidx[wave][lane] : ff;
        idxb[(size_t)q * K_NEIGH + lane] = j;
        const float gx = x0[j] - qx;
        const float gy = x1[j] - qy;
        const float gz = x2[j] - qz;
        const size_t MK = (size_t)MQ * K_NEIGH;
        const size_t o1 = (size_t)b * 3 * MK + (size_t)m * K_NEIGH + lane;
        out1[o1]          = gx;
        out1[o1 + MK]     = gy;
        out1[o1 + 2 * MK] = gz;
        if (use_xyz) {
            const size_t o0 = (size_t)b * (CCH + 3) * MK + (size_t)m * K_NEIGH + lane;
            out0[o0]          = gx;
            out0[o0 + MK]     = gy;
            out0[o0 + 2 * MK] = gz;
        }
    }
}

// ---- fallback ball (any shape): R10 structure, 256 thr, global loads ----
__global__ __launch_bounds__(256) void ball_query_xyz_kernel(
    const float* __restrict__ xyz, const float* __restrict__ new_xyz,
    int* __restrict__ idxb, float* __restrict__ out0, float* __restrict__ out1,
    int N, int M, int C, int use_xyz)
{
    __shared__ int lidx[4][K_NEIGH];
    const int wave = threadIdx.x >> 6;
    const int lane = threadIdx.x & 63;
    const int q = blockIdx.x * 4 + wave;
    const int b = q / M;
    const int m = q - b * M;

    const float* xb = xyz + (size_t)b * 3 * N;
    const float* x0 = xb;
    const float* x1 = xb + N;
    const float* x2 = xb + 2 * N;
    const float* nb = new_xyz + (size_t)b * 3 * M;
    const float qx = nb[m];
    const float qy = nb[M + m];
    const float qz = nb[2 * M + m];

    int cnt = 0;
    int ff  = 0;
    const unsigned long long below = (1ull << lane) - 1ull;

    for (int t0 = 0; t0 < N; t0 += 64) {
        const int i = t0 + lane;
        const float dx = x0[i] - qx;
        const float dy = x1[i] - qy;
        const float dz = x2[i] - qz;
        const float d2 = __fadd_rn(__fadd_rn(__fmul_rn(dx, dx), __fmul_rn(dy, dy)),
                                   __fmul_rn(dz, dz));
        const bool in_ball = d2 < R2_F32;
        const unsigned long long mask = __ballot(in_ball);
        if (mask) {
            if (cnt == 0) ff = t0 + (__ffsll(mask) - 1);
            if (in_ball) {
                const int pos = cnt + __popcll(mask & below);
                if (pos < K_NEIGH) lidx[wave][pos] = i;
            }
            cnt += __popcll(mask);
            if (cnt >= K_NEIGH) break;
        }
    }

    asm volatile("s_waitcnt lgkmcnt(0)" ::: "memory");

    if (lane < K_NEIGH) {
        const int j = (lane < cnt) ? lidx[wave][lane] : ff;
        idxb[(size_t)q * K_NEIGH + lane] = j;
        const float gx = x0[j] - qx;
        const float gy = x1[j] - qy;
        const float gz = x2[j] - qz;
        const size_t MK = (size_t)M * K_NEIGH;
        const size_t o1 = (size_t)b * 3 * MK + (size_t)m * K_NEIGH + lane;
        out1[o1]          = gx;
        out1[o1 + MK]     = gy;
        out1[o1 + 2 * MK] = gz;
        if (use_xyz) {
            const size_t o0 = (size_t)b * (C + 3) * MK + (size_t)m * K_NEIGH + lane;
            out0[o0]          = gx;
            out0[o0 + MK]     = gy;
            out0[o0 + 2 * MK] = gz;
        }
    }
}

// Fixed geometry: B=4, N=8192, M=2048, C=128. Grid = 256 blocks x 1024 thr.
// One pass, plain float4 stores (R12-validated: runs at write roofline).
__global__ __launch_bounds__(1024, 4) void gather_onepass_kernel(
    const float* __restrict__ feat,  // (B,C,N)
    const int* __restrict__ idxb,    // (B*M,K)
    float* __restrict__ out0,        // (B,CO,M,K)
    int use_xyz)
{
    __shared__ float sf[2 * NPTS];   // 64 KB: [0,N) = ch c0, [N,2N) = ch c0+1

    const int t   = threadIdx.x;
    const int bid = blockIdx.x;
    const int b   = (bid & 7) >> 1;                 // 0..3
    const int cg  = ((bid >> 3) << 1) | (bid & 1);  // 0..63
    const int c0  = cg * 2;

    // ---- Phase A: idx prefetch (regs) + feat stage (LDS) ----
    const int4* ip4 = (const int4*)(idxb + (size_t)b * MQ * K_NEIGH);
    int4 jj[16];
    #pragma unroll
    for (int i = 0; i < 16; ++i) jj[i] = ip4[i * 1024 + t];

    const float4* fv = (const float4*)(feat + ((size_t)b * CCH + c0) * NPTS);
    #pragma unroll
    for (int r = 0; r < 4; ++r)
        ((float4*)sf)[t + r * 1024] = fv[t + r * 1024];
    __syncthreads();

    // ---- Phase B: pure LDS-read + plain float4 stores ----
    const size_t MK = (size_t)MQ * K_NEIGH;
    const int CO   = use_xyz ? (CCH + 3) : CCH;
    const int coff = use_xyz ? 3 : 0;
    float* o0 = out0 + ((size_t)b * CO + coff + c0) * MK;
    float* o1 = o0 + MK;

    #pragma unroll
    for (int i = 0; i < 16; ++i) {
        const int p = i * 4096 + 4 * t;      // flat (m,k) base, k-aligned x4
        const int4 j4 = jj[i];
        float4 s0, s1;
        s0.x = sf[j4.x]; s0.y = sf[j4.y]; s0.z = sf[j4.z]; s0.w = sf[j4.w];
        s1.x = sf[NPTS + j4.x]; s1.y = sf[NPTS + j4.y];
        s1.z = sf[NPTS + j4.z]; s1.w = sf[NPTS + j4.w];
        *(float4*)(o0 + p) = s0;
        *(float4*)(o1 + p) = s1;
    }
}

// Fallback gather (any shape): R1 structure.
__global__ __launch_bounds__(256) void gather_kernel(
    const float* __restrict__ xyz, const float* __restrict__ new_xyz,
    const float* __restrict__ feat, const int* __restrict__ idxb,
    float* __restrict__ out0, float* __restrict__ out1,
    int N, int M, int C, int use_xyz)
{
    const int tid = threadIdx.x;
    const int k = tid & 31;
    const int mloc = tid >> 5;
    const int mchunks = M >> 3;
    const int b = blockIdx.x / mchunks;
    const int m = (blockIdx.x - b * mchunks) * 8 + mloc;
    const int q = b * M + m;
    const int j = idxb[(size_t)q * K_NEIGH + k];
    const size_t xb = (size_t)b * 3 * N;
    const size_t nb = (size_t)b * 3 * M;
    const float gx = xyz[xb + j]         - new_xyz[nb + m];
    const float gy = xyz[xb + N + j]     - new_xyz[nb + M + m];
    const float gz = xyz[xb + 2 * N + j] - new_xyz[nb + 2 * M + m];
    const size_t MK = (size_t)M * K_NEIGH;
    const size_t o1 = (size_t)b * 3 * MK + (size_t)m * K_NEIGH + k;
    out1[o1] = gx; out1[o1 + MK] = gy; out1[o1 + 2 * MK] = gz;
    const int CO = use_xyz ? (C + 3) : C;
    size_t o0 = (size_t)b * CO * MK + (size_t)m * K_NEIGH + k;
    if (use_xyz) {
        out0[o0] = gx; out0[o0 + MK] = gy; out0[o0 + 2 * MK] = gz;
        o0 += 3 * MK;
    }
    const float* fb = feat + (size_t)b * C * N;
    #pragma unroll 4
    for (int c = 0; c < C; c += 4) {
        const float v0 = fb[(size_t)c * N + j];
        const float v1 = fb[(size_t)(c + 1) * N + j];
        const float v2 = fb[(size_t)(c + 2) * N + j];
        const float v3 = fb[(size_t)(c + 3) * N + j];
        out0[o0 + (size_t)c * MK]       = v0;
        out0[o0 + (size_t)(c + 1) * MK] = v1;
        out0[o0 + (size_t)(c + 2) * MK] = v2;
        out0[o0 + (size_t)(c + 3) * MK] = v3;
    }
}

extern "C" void kernel_launch(void* const* d_in, const int* in_sizes, int n_in,
                              void* d_out, int out_size, void* d_ws, size_t ws_size,
                              hipStream_t stream) {
    const float* new_xyz = (const float*)d_in[0];   // (B,3,M)
    const float* xyz     = (const float*)d_in[1];   // (B,3,N)
    const float* feat    = (const float*)d_in[2];   // (B,C,N)

    const int B = 4;                       // fixed by harness setup
    const int M = in_sizes[0] / (3 * B);   // 2048
    const int N = in_sizes[1] / (3 * B);   // 8192
    const int C = in_sizes[2] / (B * N);   // 128

    const long long sz_with = (long long)B * (C + 6) * M * K_NEIGH;
    const int use_xyz = (out_size == sz_with) ? 1 : 0;

    float* out0 = (float*)d_out;
    float* out1 = out0 + (size_t)B * (use_xyz ? (C + 3) : C) * M * K_NEIGH;

    int* idxb = (int*)d_ws;  // B*M*K ints = 1 MB
    const size_t idx_bytes = (size_t)B * M * K_NEIGH * sizeof(int);

    const bool fast = (B == 4) && (N == NPTS) && (M == MQ) && (C == CCH)
                      && (ws_size >= idx_bytes);

    if (fast) {
        ball_lds_kernel<<<(B * M) / 8, 512, 0, stream>>>(
            xyz, new_xyz, idxb, out0, out1, use_xyz);
        gather_onepass_kernel<<<256, 1024, 0, stream>>>(feat, idxb, out0, use_xyz);
    } else {
        ball_query_xyz_kernel<<<(B * M) / 4, 256, 0, stream>>>(
            xyz, new_xyz, idxb, out0, out1, N, M, C, use_xyz);
        gather_kernel<<<B * (M / 8), 256, 0, stream>>>(xyz, new_xyz, feat, idxb,
                                                       out0, out1, N, M, C, use_xyz);
    }
}